// Round 16
// baseline (91.278 us; speedup 1.0000x reference)
//
#include <hip/hip_runtime.h>
#include <hip/hip_bf16.h>
#include <stdint.h>

// B=4, T=1024, C=1024, H=16, D=64
// ws layout (bf16 elems): xb[4096*1024] | wqkvT[3072*1024] | woT[1024*1024]
//                       | q[4M] | k[4M] | vT[4M] | O[4M]

typedef float f32x4 __attribute__((ext_vector_type(4)));
typedef __bf16 bf16x8 __attribute__((ext_vector_type(8)));
typedef __bf16 bf16x4 __attribute__((ext_vector_type(4)));

#define GAS __attribute__((address_space(1)))
#define LAS __attribute__((address_space(3)))

// ---------------------------------------------------------------- cast x -> bf16
__global__ __launch_bounds__(256) void cast_bf16_kernel(
    const float* __restrict__ in, __bf16* __restrict__ out, int n4) {
  int i = blockIdx.x * 256 + threadIdx.x;
  if (i < n4) {
    float4 f = ((const float4*)in)[i];
    bf16x4 o;
    o[0] = (__bf16)f.x; o[1] = (__bf16)f.y; o[2] = (__bf16)f.z; o[3] = (__bf16)f.w;
    ((bf16x4*)out)[i] = o;
  }
}

// ------------------------------------------- Wq/Wk/Wv merged transpose:
// [H][C][D] fp32 -> wqkvT rows n = sec*1024 + h*64 + d, cols C (bf16)
__global__ __launch_bounds__(256) void transpose_qkv_kernel(
    const float* __restrict__ Wq, const float* __restrict__ Wk,
    const float* __restrict__ Wv, __bf16* __restrict__ dst_base) {
  __shared__ float tile[64][65];
  int z = blockIdx.z;                                  // 0..47
  const float* s = (z < 16 ? Wq : (z < 32 ? Wk : Wv)) + (size_t)(z & 15) * 65536;
  __bf16* d = dst_base + (size_t)z * 65536;            // 64 rows x 1024
  int r0 = blockIdx.x * 64;                            // C-tile
  int tx = threadIdx.x & 63, ty = threadIdx.x >> 6;
#pragma unroll
  for (int rr = ty; rr < 64; rr += 4)
    tile[rr][tx] = s[(size_t)(r0 + rr) * 64 + tx];
  __syncthreads();
#pragma unroll
  for (int rr = ty; rr < 64; rr += 4)
    d[(size_t)rr * 1024 + (r0 + tx)] = (__bf16)tile[tx][rr];
}

// ------------------------------------------- transpose f32 [rows x cols] -> bf16 [cols x rows]
__global__ __launch_bounds__(256) void transpose_cast_kernel(
    const float* __restrict__ src, __bf16* __restrict__ dst,
    int src_ld, int dst_ld) {
  __shared__ float tile[64][65];
  int r0 = blockIdx.x * 64, c0 = blockIdx.y * 64;
  int tx = threadIdx.x & 63, ty = threadIdx.x >> 6;
#pragma unroll
  for (int rr = ty; rr < 64; rr += 4)
    tile[rr][tx] = src[(size_t)(r0 + rr) * src_ld + (c0 + tx)];
  __syncthreads();
#pragma unroll
  for (int rr = ty; rr < 64; rr += 4)
    dst[(size_t)(c0 + rr) * dst_ld + (r0 + tx)] = (__bf16)tile[tx][rr];
}

// ---------------------------------------------------------------- QKV GEMM
// 128x128 tile, BK=32 (r8 measured best for this 768-block grid: 40.1µs,
// occupancy 25% — 2-3 blocks/CU TLP beats halved drains), 2-phase dbuf,
// XOR-swizzled LDS both-sides -> 0 conflicts.  Standalone kernel (no dead
// MODE branches / template siblings perturbing regalloc — r12 lesson).
// q (pre-scaled 1/8), k scatter [B,H,T,D]; V-blocks restage through LDS for
// coalesced 16B [B,H,D,T] writes (r6 win).
__global__ __launch_bounds__(256) void qkv_gemm_kernel(
    const __bf16* __restrict__ A, const __bf16* __restrict__ BT,
    __bf16* __restrict__ qo, __bf16* __restrict__ ko, __bf16* __restrict__ vo) {
  constexpr int K = 1024;
  extern __shared__ __align__(16) char smem_raw[];
  __bf16* Ash = (__bf16*)smem_raw;                 // [2][128*32]
  __bf16* Bsh = Ash + 2 * 128 * 32;                // [2][128*32]
  const int tid = threadIdx.x;
  const int wid = tid >> 6, lane = tid & 63;
  const int fr = lane & 15, fq = lane >> 4;
  const int m0 = blockIdx.x * 128, n0 = blockIdx.y * 128;
  const int wr = wid >> 1, wc = wid & 1;
  const int srow = lane >> 2;
  const int scol = (((lane & 3) ^ ((lane >> 3) & 3))) * 8;   // pre-swizzled src chunk
  const int swz = ((fq ^ ((fr >> 1) & 3))) << 3;             // read-side swizzle

  f32x4 acc[4][4] = {};

  auto stage = [&](int k0, int buf) {
#pragma unroll
    for (int i = 0; i < 2; ++i) {
      int chunk = wid * 2 + i;
      int row = chunk * 16 + srow;
      const __bf16* gA = A + (size_t)(m0 + row) * K + k0 + scol;
      const __bf16* gB = BT + (size_t)(n0 + row) * K + k0 + scol;
      __builtin_amdgcn_global_load_lds((const GAS void*)gA, (LAS void*)&Ash[buf * 4096 + chunk * 512], 16, 0, 0);
      __builtin_amdgcn_global_load_lds((const GAS void*)gB, (LAS void*)&Bsh[buf * 4096 + chunk * 512], 16, 0, 0);
    }
  };

  stage(0, 0);
  __syncthreads();
  int buf = 0;
  for (int k0 = 0; k0 < K; k0 += 32) {
    if (k0 + 32 < K) stage(k0 + 32, buf ^ 1);
    bf16x8 af[4], bfr[4];
#pragma unroll
    for (int mi = 0; mi < 4; ++mi) {
      int r = wr * 64 + mi * 16 + fr;
      af[mi] = *(const bf16x8*)&Ash[buf * 4096 + r * 32 + swz];
    }
#pragma unroll
    for (int ni = 0; ni < 4; ++ni) {
      int r = wc * 64 + ni * 16 + fr;
      bfr[ni] = *(const bf16x8*)&Bsh[buf * 4096 + r * 32 + swz];
    }
    __builtin_amdgcn_s_setprio(1);
#pragma unroll
    for (int mi = 0; mi < 4; ++mi)
#pragma unroll
      for (int ni = 0; ni < 4; ++ni)
        acc[mi][ni] = __builtin_amdgcn_mfma_f32_16x16x32_bf16(af[mi], bfr[ni], acc[mi][ni], 0, 0, 0);
    __builtin_amdgcn_s_setprio(0);
    __syncthreads();
    buf ^= 1;
  }

  if ((n0 >> 10) == 2) {
    // ---- V-block: LDS restage for coalesced transposed writes ----
    __bf16* spill = (__bf16*)smem_raw;   // aliases Ash/Bsh; safe after final sync
#pragma unroll
    for (int mi = 0; mi < 4; ++mi)
#pragma unroll
      for (int ni = 0; ni < 4; ++ni) {
        int nl = wc * 64 + ni * 16 + fr;
        int ml = wr * 64 + mi * 16 + fq * 4;   // r packed (t-consecutive)
        bf16x4 pk;
#pragma unroll
        for (int r = 0; r < 4; ++r) pk[r] = (__bf16)acc[mi][ni][r];
        *(bf16x4*)&spill[nl * 136 + ml] = pk;
      }
    __syncthreads();
    const int b = m0 >> 10, t0 = m0 & 1023;
    const int lrow = lane >> 4, lch = lane & 15;
#pragma unroll
    for (int i = 0; i < 8; ++i) {
      int nl = wid * 32 + i * 4 + lrow;
      bf16x8 v = *(const bf16x8*)&spill[nl * 136 + lch * 8];
      int nn = (n0 & 1023) + nl;               // h*64+dd
      *(bf16x8*)&vo[(((size_t)b * 16 + (nn >> 6)) * 64 + (nn & 63)) * 1024 + t0 + lch * 8] = v;
    }
    return;
  }

#pragma unroll
  for (int mi = 0; mi < 4; ++mi) {
#pragma unroll
    for (int ni = 0; ni < 4; ++ni) {
      int n = n0 + wc * 64 + ni * 16 + fr;
      int mb = m0 + wr * 64 + mi * 16 + fq * 4;
      int nl = n & 1023;
      int h = nl >> 6, dd = nl & 63;
#pragma unroll
      for (int r = 0; r < 4; ++r) {
        int m = mb + r;
        int b = m >> 10, t = m & 1023;
        float val = acc[mi][ni][r];
        if ((n >> 10) == 0) {
          qo[(((size_t)b * 16 + h) * 1024 + t) * 64 + dd] = (__bf16)(val * 0.125f);
        } else {
          ko[(((size_t)b * 16 + h) * 1024 + t) * 64 + dd] = (__bf16)val;
        }
      }
    }
  }
}

// ---------------------------------------------------------------- out-proj GEMM
// 128x128 tile, BK=64 (r10 measured best for this 256-block / 1-blk-per-CU
// grid: no inter-block TLP, so halving drain events is the win), 2-phase dbuf,
// XOR swizzle both-sides.  fp32 out + bias.
__global__ __launch_bounds__(256) void outproj_gemm_kernel(
    const __bf16* __restrict__ A, const __bf16* __restrict__ BT, int N,
    float* __restrict__ Cout, const float* __restrict__ bias) {
  constexpr int K = 1024;
  extern __shared__ __align__(16) char smem_raw[];
  __bf16* Ash = (__bf16*)smem_raw;                 // [2][128*64]
  __bf16* Bsh = Ash + 2 * 128 * 64;                // [2][128*64]
  const int tid = threadIdx.x;
  const int wid = tid >> 6, lane = tid & 63;
  const int fr = lane & 15, fq = lane >> 4;
  const int m0 = blockIdx.x * 128, n0 = blockIdx.y * 128;
  const int wr = wid >> 1, wc = wid & 1;
  const int lrow8 = lane >> 3;
  const int sc = ((lane & 7) ^ lrow8) * 8;         // pre-swizzled source col

  f32x4 acc[4][4] = {};

  auto stage = [&](int k0, int buf) {
#pragma unroll
    for (int j = 0; j < 4; ++j) {
      int cc = j * 4 + wid;                        // 0..15, wave-uniform
      int row = cc * 8 + lrow8;
      const __bf16* gA = A + (size_t)(m0 + row) * K + k0 + sc;
      const __bf16* gB = BT + (size_t)(n0 + row) * K + k0 + sc;
      __builtin_amdgcn_global_load_lds((const GAS void*)gA, (LAS void*)&Ash[buf * 8192 + cc * 512], 16, 0, 0);
      __builtin_amdgcn_global_load_lds((const GAS void*)gB, (LAS void*)&Bsh[buf * 8192 + cc * 512], 16, 0, 0);
    }
  };

  stage(0, 0);
  __syncthreads();
  int buf = 0;
  for (int k0 = 0; k0 < K; k0 += 64) {
    if (k0 + 64 < K) stage(k0 + 64, buf ^ 1);
#pragma unroll
    for (int kk = 0; kk < 2; ++kk) {
      const int ch = ((((kk << 2) | fq)) ^ (fr & 7)) * 8;
      bf16x8 af[4], bfr[4];
#pragma unroll
      for (int mi = 0; mi < 4; ++mi) {
        int r = wr * 64 + mi * 16 + fr;
        af[mi] = *(const bf16x8*)&Ash[buf * 8192 + r * 64 + ch];
      }
#pragma unroll
      for (int ni = 0; ni < 4; ++ni) {
        int r = wc * 64 + ni * 16 + fr;
        bfr[ni] = *(const bf16x8*)&Bsh[buf * 8192 + r * 64 + ch];
      }
      __builtin_amdgcn_s_setprio(1);
#pragma unroll
      for (int mi = 0; mi < 4; ++mi)
#pragma unroll
        for (int ni = 0; ni < 4; ++ni)
          acc[mi][ni] = __builtin_amdgcn_mfma_f32_16x16x32_bf16(af[mi], bfr[ni], acc[mi][ni], 0, 0, 0);
      __builtin_amdgcn_s_setprio(0);
    }
    __syncthreads();
    buf ^= 1;
  }

#pragma unroll
  for (int mi = 0; mi < 4; ++mi) {
#pragma unroll
    for (int ni = 0; ni < 4; ++ni) {
      int n = n0 + wc * 64 + ni * 16 + fr;
      int mb = m0 + wr * 64 + mi * 16 + fq * 4;
#pragma unroll
      for (int r = 0; r < 4; ++r) {
        int m = mb + r;
        Cout[(size_t)m * N + n] = acc[mi][ni][r] + bias[n];
      }
    }
  }
}

// ---------------------------------------------------------------- flash attention (causal)
// 1024 blocks, 256 threads = 4 waves.  One q-tile per block (qt = 15 - bid>>6:
// LPT order).  bh = bid & 63 -> 16 blocks/bh share bid%8 -> same XCD -> K/V
// L2-resident.  Defer-max (T13, THR=8).  Psh XOR-swizzled (40960B LDS).
__global__ __launch_bounds__(256) void attn_fwd_kernel(
    const __bf16* __restrict__ Q, const __bf16* __restrict__ Kg,
    const __bf16* __restrict__ Vt, __bf16* __restrict__ O) {
  __shared__ __align__(16) __bf16 Ksh[2][64 * 64];
  __shared__ __align__(16) __bf16 VTs[2][64 * 64];
  __shared__ __align__(16) __bf16 Psh[4][16 * 64];   // swizzled, no pad

  const int bid = blockIdx.x;
  const int qt = 15 - (bid >> 6);
  const int bh = bid & 63;
  const int b = bh >> 4, h = bh & 15;
  const size_t base = (size_t)bh * 1024 * 64;
  const int tid = threadIdx.x, wid = tid >> 6, lane = tid & 63;
  const int fr = lane & 15, fq = lane >> 4;
  const int q0 = qt * 64;

  bf16x8 qf[2];
  {
    int qr = q0 + wid * 16 + fr;
    qf[0] = *(const bf16x8*)&Q[base + (size_t)qr * 64 + fq * 8];
    qf[1] = *(const bf16x8*)&Q[base + (size_t)qr * 64 + 32 + fq * 8];
  }
  f32x4 oacc[4] = {};
  float m = -1e30f, l = 0.f;   // state for row q = q0 + wid*16 + fr

  const int lrow8 = lane >> 3;
  const int schunk = (lane & 7) ^ lrow8;

  auto stage = [&](int st, int buf) {
    const int s0 = st * 64;
#pragma unroll
    for (int i = 0; i < 2; ++i) {
      int rowbase = i * 32 + wid * 8;
      int row = rowbase + lrow8;
      const __bf16* gK = Kg + base + (size_t)(s0 + row) * 64 + schunk * 8;
      __builtin_amdgcn_global_load_lds((const GAS void*)gK,
          (LAS void*)&Ksh[buf][rowbase * 64], 16, 0, 0);
      const __bf16* gV = Vt + base + (size_t)row * 1024 + s0 + schunk * 8;
      __builtin_amdgcn_global_load_lds((const GAS void*)gV,
          (LAS void*)&VTs[buf][rowbase * 64], 16, 0, 0);
    }
  };

  auto compute = [&](int buf, int s0, bool maskT) {
    // S^T = K Q^T : lane holds s = sf*16+fq*4+r, q = fr
    f32x4 s[4];
    __builtin_amdgcn_s_setprio(1);
#pragma unroll
    for (int sf = 0; sf < 4; ++sf) {
      int row = sf * 16 + fr, rx = fr & 7;
      bf16x8 kf0 = *(const bf16x8*)&Ksh[buf][row * 64 + ((fq ^ rx) << 3)];
      f32x4 z = {};
      s[sf] = __builtin_amdgcn_mfma_f32_16x16x32_bf16(kf0, qf[0], z, 0, 0, 0);
      bf16x8 kf1 = *(const bf16x8*)&Ksh[buf][row * 64 + (((4 + fq) ^ rx) << 3)];
      s[sf] = __builtin_amdgcn_mfma_f32_16x16x32_bf16(kf1, qf[1], s[sf], 0, 0, 0);
    }
    __builtin_amdgcn_s_setprio(0);

    const int qg = q0 + wid * 16 + fr;
    float sv[4][4];
    float mx = -1e30f;
#pragma unroll
    for (int sf = 0; sf < 4; ++sf)
#pragma unroll
      for (int r = 0; r < 4; ++r) {
        float x = s[sf][r];
        if (maskT) { int sg = s0 + sf * 16 + fq * 4 + r; if (sg > qg) x = -1e30f; }
        sv[sf][r] = x;
        mx = fmaxf(mx, x);
      }
    mx = fmaxf(mx, __shfl_xor(mx, 16));
    mx = fmaxf(mx, __shfl_xor(mx, 32));
    // defer-max: rescale only when tile max grew past THR=8 (rare)
    if (__any(mx - m > 8.0f)) {
      float mnew = fmaxf(m, mx);
      float alpha = __expf(m - mnew);
      m = mnew;
      l *= alpha;
      float ar[4];
#pragma unroll
      for (int r = 0; r < 4; ++r) ar[r] = __shfl(alpha, (lane & 48) | (fq * 4 + r));
#pragma unroll
      for (int df = 0; df < 4; ++df)
#pragma unroll
        for (int r = 0; r < 4; ++r) oacc[df][r] *= ar[r];
    }
    float rs = 0.f;
#pragma unroll
    for (int sf = 0; sf < 4; ++sf) {
      bf16x4 pk;
#pragma unroll
      for (int r = 0; r < 4; ++r) {
        float p = __expf(sv[sf][r] - m);
        rs += p;
        pk[r] = (__bf16)p;
      }
      // P[q=fr][s]: chunk16B = (2sf+(fq>>1)) ^ (fr&7), +4 elems if fq odd
      *(bf16x4*)&Psh[wid][fr * 64 + ((((sf << 1) | (fq >> 1)) ^ (fr & 7)) << 3) + ((fq & 1) << 2)] = pk;
    }
    rs += __shfl_xor(rs, 16);
    rs += __shfl_xor(rs, 32);
    l += rs;

    // O += P V : A = P rows (q_local=fr), B = VT rows (d)
    __builtin_amdgcn_s_setprio(1);
#pragma unroll
    for (int kk = 0; kk < 2; ++kk) {
      bf16x8 pf = *(const bf16x8*)&Psh[wid][fr * 64 + ((((kk << 2) | fq) ^ (fr & 7)) << 3)];
#pragma unroll
      for (int df = 0; df < 4; ++df) {
        int row = df * 16 + fr;
        bf16x8 vf = *(const bf16x8*)&VTs[buf][row * 64 + ((((kk << 2) | fq) ^ (fr & 7)) << 3)];
        oacc[df] = __builtin_amdgcn_mfma_f32_16x16x32_bf16(pf, vf, oacc[df], 0, 0, 0);
      }
    }
    __builtin_amdgcn_s_setprio(0);
  };

  stage(0, 0);
  __syncthreads();
  int cur = 0;
  for (int st = 0; st <= qt; ++st) {
    if (st < qt) stage(st + 1, cur ^ 1);
    compute(cur, st * 64, st == qt);
    __syncthreads();
    cur ^= 1;
  }

  // epilogue
  float lr[4];
#pragma unroll
  for (int r = 0; r < 4; ++r) lr[r] = __shfl(l, (lane & 48) | (fq * 4 + r));
#pragma unroll
  for (int r = 0; r < 4; ++r) {
    float inv = 1.0f / lr[r];
    int t = q0 + wid * 16 + fq * 4 + r;
    size_t orow = ((size_t)b * 1024 + t) * 1024 + h * 64;
#pragma unroll
    for (int df = 0; df < 4; ++df)
      O[orow + df * 16 + fr] = (__bf16)(oacc[df][r] * inv);
  }
}

// ---------------------------------------------------------------- launch
extern "C" void kernel_launch(void* const* d_in, const int* in_sizes, int n_in,
                              void* d_out, int out_size, void* d_ws, size_t ws_size,
                              hipStream_t stream) {
  const float* x  = (const float*)d_in[0];
  const float* Wq = (const float*)d_in[1];
  const float* Wk = (const float*)d_in[2];
  const float* Wv = (const float*)d_in[3];
  const float* Wo = (const float*)d_in[4];
  const float* bo = (const float*)d_in[5];
  float* out = (float*)d_out;

  __bf16* xb    = (__bf16*)d_ws;                    // 4096x1024
  __bf16* wqkvT = xb + (size_t)4096 * 1024;         // 3072x1024
  __bf16* woT   = wqkvT + (size_t)3072 * 1024;      // 1024x1024
  __bf16* qb    = woT + (size_t)1024 * 1024;        // [B,H,T,D]
  __bf16* kb    = qb + (size_t)4 * 16 * 1024 * 64;  // [B,H,T,D]
  __bf16* vtb   = kb + (size_t)4 * 16 * 1024 * 64;  // [B,H,D,T]
  __bf16* Ob    = vtb + (size_t)4 * 16 * 1024 * 64; // [B*T, H*D]

  cast_bf16_kernel<<<4096, 256, 0, stream>>>(x, xb, 4194304 / 4);
  transpose_qkv_kernel<<<dim3(16, 1, 48), 256, 0, stream>>>(Wq, Wk, Wv, wqkvT);
  transpose_cast_kernel<<<dim3(16, 16), 256, 0, stream>>>(Wo, woT, 1024, 1024);

  // QKV projection: BK=32 standalone (r8-best for 768-block grid)
  qkv_gemm_kernel<<<dim3(32, 24), 256, 34816, stream>>>(xb, wqkvT, qb, kb, vtb);

  // causal flash attention (one q-tile per block, LPT order, XCD-grouped by bh)
  attn_fwd_kernel<<<1024, 256, 0, stream>>>(qb, kb, vtb, Ob);

  // output projection + bias: BK=64 standalone (r10-best for 1-blk/CU grid)
  outproj_gemm_kernel<<<dim3(32, 8), 256, 65536, stream>>>(Ob, woT, 1024, out, bo);
}

// Round 17
// 82.077 us; speedup vs baseline: 1.1121x; 1.1121x over previous
//
#include <hip/hip_runtime.h>
#include <hip/hip_bf16.h>
#include <stdint.h>

// B=4, T=1024, C=1024, H=16, D=64
// ws layout (bf16 elems): xb[4096*1024] | wqkvT[3072*1024] | woT[1024*1024]
//                       | q[4M] | k[4M] | vT[4M] | O[4M]

typedef float f32x4 __attribute__((ext_vector_type(4)));
typedef __bf16 bf16x8 __attribute__((ext_vector_type(8)));
typedef __bf16 bf16x4 __attribute__((ext_vector_type(4)));

#define GAS __attribute__((address_space(1)))
#define LAS __attribute__((address_space(3)))

// ---------------------------------------------------------------- merged prep
// One launch, 5120 blocks:
//   [0,4096)    : cast x fp32 -> bf16 (float4/lane)
//   [4096,4864) : Wq/Wk/Wv [H][C][D] -> wqkvT rows n=sec*1024+h*64+d, cols C
//   [4864,5120) : Wo [1024][1024] -> woT (transpose+cast)
// All three are independent (disjoint in/out); merging removes 2 launch gaps.
__global__ __launch_bounds__(256) void prep_kernel(
    const float* __restrict__ x, const float* __restrict__ Wq,
    const float* __restrict__ Wk, const float* __restrict__ Wv,
    const float* __restrict__ Wo, __bf16* __restrict__ xb,
    __bf16* __restrict__ wqkvT, __bf16* __restrict__ woT) {
  __shared__ float tile[64][65];
  int bx = blockIdx.x;
  if (bx < 4096) {
    int i = bx * 256 + threadIdx.x;
    float4 f = ((const float4*)x)[i];
    bf16x4 o;
    o[0] = (__bf16)f.x; o[1] = (__bf16)f.y; o[2] = (__bf16)f.z; o[3] = (__bf16)f.w;
    ((bf16x4*)xb)[i] = o;
    return;
  }
  int tx = threadIdx.x & 63, ty = threadIdx.x >> 6;
  if (bx < 4864) {
    bx -= 4096;                                        // 0..767
    int z = bx >> 4;                                   // 0..47
    int r0 = (bx & 15) * 64;                           // C-tile
    const float* s = (z < 16 ? Wq : (z < 32 ? Wk : Wv)) + (size_t)(z & 15) * 65536;
    __bf16* d = wqkvT + (size_t)z * 65536;             // 64 rows x 1024
#pragma unroll
    for (int rr = ty; rr < 64; rr += 4)
      tile[rr][tx] = s[(size_t)(r0 + rr) * 64 + tx];
    __syncthreads();
#pragma unroll
    for (int rr = ty; rr < 64; rr += 4)
      d[(size_t)rr * 1024 + (r0 + tx)] = (__bf16)tile[tx][rr];
  } else {
    bx -= 4864;                                        // 0..255
    int r0 = (bx & 15) * 64, c0 = (bx >> 4) * 64;
#pragma unroll
    for (int rr = ty; rr < 64; rr += 4)
      tile[rr][tx] = Wo[(size_t)(r0 + rr) * 1024 + (c0 + tx)];
    __syncthreads();
#pragma unroll
    for (int rr = ty; rr < 64; rr += 4)
      woT[(size_t)(c0 + rr) * 1024 + (r0 + tx)] = (__bf16)tile[tx][rr];
  }
}

// ---------------------------------------------------------------- GEMM (A row-major, BT = B^T row-major)
// 128x128 tile, BK=64, 256 threads (4 waves 2x2, each 64x64), 2-phase dbuf.
// XOR swizzle c8 ^= row&7 on 128B rows, both-sides -> conflict-free.
// (r10/r15 measured-best total config — unchanged.)
// MODE 0: q (pre-scaled 1/8), k scatter [B,H,T,D]; V-blocks (sec==2) restage
//         the tile through LDS for fully-coalesced 16B vT writes (r6 win).
// MODE 1: fp32 out + bias
template <int MODE>
__global__ __launch_bounds__(256) void gemm_bt_kernel(
    const __bf16* __restrict__ A, const __bf16* __restrict__ BT, int N,
    __bf16* __restrict__ qo, __bf16* __restrict__ ko, __bf16* __restrict__ vo,
    float* __restrict__ Cout, const float* __restrict__ bias) {
  constexpr int K = 1024;
  extern __shared__ __align__(16) char smem_raw[];
  __bf16* Ash = (__bf16*)smem_raw;                 // [2][128*64]
  __bf16* Bsh = Ash + 2 * 128 * 64;                // [2][128*64]
  const int tid = threadIdx.x;
  const int wid = tid >> 6, lane = tid & 63;
  const int fr = lane & 15, fq = lane >> 4;
  const int m0 = blockIdx.x * 128, n0 = blockIdx.y * 128;
  const int wr = wid >> 1, wc = wid & 1;
  const int lrow8 = lane >> 3;                     // row-within-8 for staging
  const int sc = ((lane & 7) ^ lrow8) * 8;         // pre-swizzled source col (elems)

  f32x4 acc[4][4] = {};

  auto stage = [&](int k0, int buf) {
#pragma unroll
    for (int j = 0; j < 4; ++j) {
      int cc = j * 4 + wid;                        // 0..15, wave-uniform
      int row = cc * 8 + lrow8;
      const __bf16* gA = A + (size_t)(m0 + row) * K + k0 + sc;
      const __bf16* gB = BT + (size_t)(n0 + row) * K + k0 + sc;
      __builtin_amdgcn_global_load_lds((const GAS void*)gA, (LAS void*)&Ash[buf * 8192 + cc * 512], 16, 0, 0);
      __builtin_amdgcn_global_load_lds((const GAS void*)gB, (LAS void*)&Bsh[buf * 8192 + cc * 512], 16, 0, 0);
    }
  };

  stage(0, 0);
  __syncthreads();
  int buf = 0;
  for (int k0 = 0; k0 < K; k0 += 64) {
    if (k0 + 64 < K) stage(k0 + 64, buf ^ 1);
#pragma unroll
    for (int kk = 0; kk < 2; ++kk) {
      const int ch = ((((kk << 2) | fq)) ^ (fr & 7)) * 8;   // swizzled read col (elems)
      bf16x8 af[4], bfr[4];
#pragma unroll
      for (int mi = 0; mi < 4; ++mi) {
        int r = wr * 64 + mi * 16 + fr;
        af[mi] = *(const bf16x8*)&Ash[buf * 8192 + r * 64 + ch];
      }
#pragma unroll
      for (int ni = 0; ni < 4; ++ni) {
        int r = wc * 64 + ni * 16 + fr;
        bfr[ni] = *(const bf16x8*)&Bsh[buf * 8192 + r * 64 + ch];
      }
      __builtin_amdgcn_s_setprio(1);
#pragma unroll
      for (int mi = 0; mi < 4; ++mi)
#pragma unroll
        for (int ni = 0; ni < 4; ++ni)
          acc[mi][ni] = __builtin_amdgcn_mfma_f32_16x16x32_bf16(af[mi], bfr[ni], acc[mi][ni], 0, 0, 0);
      __builtin_amdgcn_s_setprio(0);
    }
    __syncthreads();
    buf ^= 1;
  }

  if (MODE == 0 && (n0 >> 10) == 2) {
    // ---- V-block: LDS restage for coalesced transposed writes ----
    __bf16* spill = (__bf16*)smem_raw;   // aliases Ash/Bsh; safe after final sync
#pragma unroll
    for (int mi = 0; mi < 4; ++mi)
#pragma unroll
      for (int ni = 0; ni < 4; ++ni) {
        int nl = wc * 64 + ni * 16 + fr;
        int ml = wr * 64 + mi * 16 + fq * 4;   // r packed (t-consecutive)
        bf16x4 pk;
#pragma unroll
        for (int r = 0; r < 4; ++r) pk[r] = (__bf16)acc[mi][ni][r];
        *(bf16x4*)&spill[nl * 136 + ml] = pk;
      }
    __syncthreads();
    const int b = m0 >> 10, t0 = m0 & 1023;
    const int lrow = lane >> 4, lch = lane & 15;
#pragma unroll
    for (int i = 0; i < 8; ++i) {
      int nl = wid * 32 + i * 4 + lrow;
      bf16x8 v = *(const bf16x8*)&spill[nl * 136 + lch * 8];
      int nn = (n0 & 1023) + nl;               // h*64+dd
      *(bf16x8*)&vo[(((size_t)b * 16 + (nn >> 6)) * 64 + (nn & 63)) * 1024 + t0 + lch * 8] = v;
    }
    return;
  }

#pragma unroll
  for (int mi = 0; mi < 4; ++mi) {
#pragma unroll
    for (int ni = 0; ni < 4; ++ni) {
      int n = n0 + wc * 64 + ni * 16 + fr;
      int mb = m0 + wr * 64 + mi * 16 + fq * 4;
#pragma unroll
      for (int r = 0; r < 4; ++r) {
        int m = mb + r;
        float val = acc[mi][ni][r];
        if (MODE == 0) {
          int nl = n & 1023;
          int h = nl >> 6, dd = nl & 63;
          int b = m >> 10, t = m & 1023;
          if ((n >> 10) == 0) {
            qo[(((size_t)b * 16 + h) * 1024 + t) * 64 + dd] = (__bf16)(val * 0.125f);
          } else {
            ko[(((size_t)b * 16 + h) * 1024 + t) * 64 + dd] = (__bf16)val;
          }
        } else {
          Cout[(size_t)m * N + n] = val + bias[n];
        }
      }
    }
  }
}

// ---------------------------------------------------------------- flash attention (causal)
// 1024 blocks, 256 threads = 4 waves.  One q-tile per block (qt = 15 - bid>>6:
// LPT order).  bh = bid & 63 -> 16 blocks/bh share bid%8 -> same XCD -> K/V
// L2-resident.  Defer-max (T13, THR=8).  Psh XOR-swizzled (40960B LDS).
__global__ __launch_bounds__(256) void attn_fwd_kernel(
    const __bf16* __restrict__ Q, const __bf16* __restrict__ Kg,
    const __bf16* __restrict__ Vt, __bf16* __restrict__ O) {
  __shared__ __align__(16) __bf16 Ksh[2][64 * 64];
  __shared__ __align__(16) __bf16 VTs[2][64 * 64];
  __shared__ __align__(16) __bf16 Psh[4][16 * 64];   // swizzled, no pad

  const int bid = blockIdx.x;
  const int qt = 15 - (bid >> 6);
  const int bh = bid & 63;
  const int b = bh >> 4, h = bh & 15;
  const size_t base = (size_t)bh * 1024 * 64;
  const int tid = threadIdx.x, wid = tid >> 6, lane = tid & 63;
  const int fr = lane & 15, fq = lane >> 4;
  const int q0 = qt * 64;

  bf16x8 qf[2];
  {
    int qr = q0 + wid * 16 + fr;
    qf[0] = *(const bf16x8*)&Q[base + (size_t)qr * 64 + fq * 8];
    qf[1] = *(const bf16x8*)&Q[base + (size_t)qr * 64 + 32 + fq * 8];
  }
  f32x4 oacc[4] = {};
  float m = -1e30f, l = 0.f;   // state for row q = q0 + wid*16 + fr

  const int lrow8 = lane >> 3;
  const int schunk = (lane & 7) ^ lrow8;

  auto stage = [&](int st, int buf) {
    const int s0 = st * 64;
#pragma unroll
    for (int i = 0; i < 2; ++i) {
      int rowbase = i * 32 + wid * 8;
      int row = rowbase + lrow8;
      const __bf16* gK = Kg + base + (size_t)(s0 + row) * 64 + schunk * 8;
      __builtin_amdgcn_global_load_lds((const GAS void*)gK,
          (LAS void*)&Ksh[buf][rowbase * 64], 16, 0, 0);
      const __bf16* gV = Vt + base + (size_t)row * 1024 + s0 + schunk * 8;
      __builtin_amdgcn_global_load_lds((const GAS void*)gV,
          (LAS void*)&VTs[buf][rowbase * 64], 16, 0, 0);
    }
  };

  auto compute = [&](int buf, int s0, bool maskT) {
    // S^T = K Q^T : lane holds s = sf*16+fq*4+r, q = fr
    f32x4 s[4];
    __builtin_amdgcn_s_setprio(1);
#pragma unroll
    for (int sf = 0; sf < 4; ++sf) {
      int row = sf * 16 + fr, rx = fr & 7;
      bf16x8 kf0 = *(const bf16x8*)&Ksh[buf][row * 64 + ((fq ^ rx) << 3)];
      f32x4 z = {};
      s[sf] = __builtin_amdgcn_mfma_f32_16x16x32_bf16(kf0, qf[0], z, 0, 0, 0);
      bf16x8 kf1 = *(const bf16x8*)&Ksh[buf][row * 64 + (((4 + fq) ^ rx) << 3)];
      s[sf] = __builtin_amdgcn_mfma_f32_16x16x32_bf16(kf1, qf[1], s[sf], 0, 0, 0);
    }
    __builtin_amdgcn_s_setprio(0);

    const int qg = q0 + wid * 16 + fr;
    float sv[4][4];
    float mx = -1e30f;
#pragma unroll
    for (int sf = 0; sf < 4; ++sf)
#pragma unroll
      for (int r = 0; r < 4; ++r) {
        float x = s[sf][r];
        if (maskT) { int sg = s0 + sf * 16 + fq * 4 + r; if (sg > qg) x = -1e30f; }
        sv[sf][r] = x;
        mx = fmaxf(mx, x);
      }
    mx = fmaxf(mx, __shfl_xor(mx, 16));
    mx = fmaxf(mx, __shfl_xor(mx, 32));
    // defer-max: rescale only when tile max grew past THR=8 (rare)
    if (__any(mx - m > 8.0f)) {
      float mnew = fmaxf(m, mx);
      float alpha = __expf(m - mnew);
      m = mnew;
      l *= alpha;
      float ar[4];
#pragma unroll
      for (int r = 0; r < 4; ++r) ar[r] = __shfl(alpha, (lane & 48) | (fq * 4 + r));
#pragma unroll
      for (int df = 0; df < 4; ++df)
#pragma unroll
        for (int r = 0; r < 4; ++r) oacc[df][r] *= ar[r];
    }
    float rs = 0.f;
#pragma unroll
    for (int sf = 0; sf < 4; ++sf) {
      bf16x4 pk;
#pragma unroll
      for (int r = 0; r < 4; ++r) {
        float p = __expf(sv[sf][r] - m);
        rs += p;
        pk[r] = (__bf16)p;
      }
      // P[q=fr][s]: chunk16B = (2sf+(fq>>1)) ^ (fr&7), +4 elems if fq odd
      *(bf16x4*)&Psh[wid][fr * 64 + ((((sf << 1) | (fq >> 1)) ^ (fr & 7)) << 3) + ((fq & 1) << 2)] = pk;
    }
    rs += __shfl_xor(rs, 16);
    rs += __shfl_xor(rs, 32);
    l += rs;

    // O += P V : A = P rows (q_local=fr), B = VT rows (d)
    __builtin_amdgcn_s_setprio(1);
#pragma unroll
    for (int kk = 0; kk < 2; ++kk) {
      bf16x8 pf = *(const bf16x8*)&Psh[wid][fr * 64 + ((((kk << 2) | fq) ^ (fr & 7)) << 3)];
#pragma unroll
      for (int df = 0; df < 4; ++df) {
        int row = df * 16 + fr;
        bf16x8 vf = *(const bf16x8*)&VTs[buf][row * 64 + ((((kk << 2) | fq) ^ (fr & 7)) << 3)];
        oacc[df] = __builtin_amdgcn_mfma_f32_16x16x32_bf16(pf, vf, oacc[df], 0, 0, 0);
      }
    }
    __builtin_amdgcn_s_setprio(0);
  };

  stage(0, 0);
  __syncthreads();
  int cur = 0;
  for (int st = 0; st <= qt; ++st) {
    if (st < qt) stage(st + 1, cur ^ 1);
    compute(cur, st * 64, st == qt);
    __syncthreads();
    cur ^= 1;
  }

  // epilogue
  float lr[4];
#pragma unroll
  for (int r = 0; r < 4; ++r) lr[r] = __shfl(l, (lane & 48) | (fq * 4 + r));
#pragma unroll
  for (int r = 0; r < 4; ++r) {
    float inv = 1.0f / lr[r];
    int t = q0 + wid * 16 + fq * 4 + r;
    size_t orow = ((size_t)b * 1024 + t) * 1024 + h * 64;
#pragma unroll
    for (int df = 0; df < 4; ++df)
      O[orow + df * 16 + fr] = (__bf16)(oacc[df][r] * inv);
  }
}

// ---------------------------------------------------------------- launch
extern "C" void kernel_launch(void* const* d_in, const int* in_sizes, int n_in,
                              void* d_out, int out_size, void* d_ws, size_t ws_size,
                              hipStream_t stream) {
  const float* x  = (const float*)d_in[0];
  const float* Wq = (const float*)d_in[1];
  const float* Wk = (const float*)d_in[2];
  const float* Wv = (const float*)d_in[3];
  const float* Wo = (const float*)d_in[4];
  const float* bo = (const float*)d_in[5];
  float* out = (float*)d_out;

  __bf16* xb    = (__bf16*)d_ws;                    // 4096x1024
  __bf16* wqkvT = xb + (size_t)4096 * 1024;         // 3072x1024
  __bf16* woT   = wqkvT + (size_t)3072 * 1024;      // 1024x1024
  __bf16* qb    = woT + (size_t)1024 * 1024;        // [B,H,T,D]
  __bf16* kb    = qb + (size_t)4 * 16 * 1024 * 64;  // [B,H,T,D]
  __bf16* vtb   = kb + (size_t)4 * 16 * 1024 * 64;  // [B,H,D,T]
  __bf16* Ob    = vtb + (size_t)4 * 16 * 1024 * 64; // [B*T, H*D]

  // merged prep: cast + both weight transposes in ONE launch
  prep_kernel<<<5120, 256, 0, stream>>>(x, Wq, Wk, Wv, Wo, xb, wqkvT, woT);

  // QKV projection: [4096,1024] @ [1024,3072]   (r15 config: BK=64, 64KB dbuf)
  gemm_bt_kernel<0><<<dim3(32, 24), 256, 65536, stream>>>(xb, wqkvT, 3072, qb, kb, vtb, nullptr, nullptr);

  // causal flash attention (one q-tile per block, LPT order, XCD-grouped by bh)
  attn_fwd_kernel<<<1024, 256, 0, stream>>>(qb, kb, vtb, Ob);

  // output projection + bias: [4096,1024] @ [1024,1024]   (r15 config: BK=64)
  gemm_bt_kernel<1><<<dim3(32, 8), 256, 65536, stream>>>(Ob, woT, 1024,
      nullptr, nullptr, nullptr, out, bo);
}